// Round 1
// baseline (767.830 us; speedup 1.0000x reference)
//
#include <hip/hip_runtime.h>
#include <cstdint>
#include <cstddef>

typedef __bf16 bf16;
typedef __bf16 bf16x8 __attribute__((ext_vector_type(8)));
typedef float  f32x4  __attribute__((ext_vector_type(4)));

constexpr int S_      = 2048;
constexpr int H_      = 2048;
constexpr int NH_     = 16;
constexpr int KV_RANK_= 256;
constexpr int EXP_    = 8;
constexpr int INTER_  = 1408;
constexpr int QH_     = 128;
constexpr float EPS_  = 1e-6f;

__device__ inline void gload16(const void* g, void* l) {
  __builtin_amdgcn_global_load_lds(
      (const __attribute__((address_space(1))) void*)g,
      (__attribute__((address_space(3))) void*)l, 16, 0, 0);
}

#define CFENCE() asm volatile("" ::: "memory")

enum { EPI_BF16 = 0, EPI_F32 = 1, EPI_ADD = 2, EPI_SILU = 3, EPI_ATOM = 4 };

// ---------------------------------------------------------------------------
// MFMA GEMM: C[M,N] (+)= A[M,K] @ B[N,K]^T   (BK=64, TILE in {64,128})
//  4 waves as 2x2, each wave (TILE/2)^2 via FRxFRx2 mfma_f32_16x16x32_bf16.
//  XOR-swizzled LDS (conflict-free), staging via global_load_lds width=16.
//  kPerE>0: flat-K MoE, B base hops every kPerE cols by bExpStride.
// ---------------------------------------------------------------------------
template <int EPI, typename TB, int TILE>
__global__ void __launch_bounds__(256, 3) gemm_bt(
    const bf16* __restrict__ A, const TB* __restrict__ B,
    void* __restrict__ Cv, const float* __restrict__ aux,
    int M, int N, int K, int lda, int ldb, int ldc,
    long zA, long zB, long zC, long auxZ, int auxRS,
    int kPerE, long bExpStride, int expBasePerZ)
{
  constexpr int FR = TILE / 32;
  const int tileN = blockIdx.x * TILE;
  const int tileM = blockIdx.y * TILE;
  const int z = blockIdx.z;
  A += (long)z * zA;

  __shared__ __align__(16) bf16 As[TILE * 64];
  __shared__ __align__(16) TB   Bs[TILE * 64];
  char* AsB = (char*)As;
  char* BsB = (char*)Bs;

  const int tid  = threadIdx.x;
  const int lane = tid & 63;
  const int wave = tid >> 6;
  const int wr = wave >> 1, wc = wave & 1;
  const int quad = lane >> 4, r16 = lane & 15;

  const int ldbe = (kPerE > 0) ? kPerE : ldb;
  const TB* BzBase = (kPerE > 0) ? (B + (long)z * expBasePerZ * bExpStride)
                                 : (B + (long)z * zB);

  constexpr int IA = TILE / 32;
  const bf16* aG[IA]; char* aL[IA];
#pragma unroll
  for (int i = 0; i < IA; i++) {
    int n = (wave * IA + i) * 64 + lane;
    int row = n >> 3, cp = n & 7;
    int cc = (cp ^ (row & 7)) << 3;
    int rowg = tileM + row; if (rowg > M - 1) rowg = M - 1;
    aG[i] = A + (long)rowg * lda + cc;
    aL[i] = AsB + (long)(wave * IA + i) * 1024;
  }
  constexpr int IB = (sizeof(TB) == 4) ? (TILE / 16) : (TILE / 32);
  const TB* bG[IB]; char* bL[IB];
#pragma unroll
  for (int i = 0; i < IB; i++) {
    int n = (wave * IB + i) * 64 + lane;
    int row, cc;
    if constexpr (sizeof(TB) == 4) { row = n >> 4; cc = ((n & 15) ^ (row & 15)) << 2; }
    else                           { row = n >> 3; cc = ((n & 7)  ^ (row & 7))  << 3; }
    int rowg = tileN + row; if (rowg > N - 1) rowg = N - 1;
    bG[i] = BzBase + (long)rowg * ldbe + cc;
    bL[i] = BsB + (long)(wave * IB + i) * 1024;
  }

  int aOff[FR], bOff[FR];
#pragma unroll
  for (int i = 0; i < FR; i++) {
    int row = wr * (TILE / 2) + i * 16 + r16;
    aOff[i] = row * 128 + ((quad ^ (row & 7)) << 4);
  }
#pragma unroll
  for (int j = 0; j < FR; j++) {
    int row = wc * (TILE / 2) + j * 16 + r16;
    if constexpr (sizeof(TB) == 4) bOff[j] = row * 256 + (((2 * quad) ^ (row & 15)) << 4);
    else                           bOff[j] = row * 128 + ((quad ^ (row & 7)) << 4);
  }

  f32x4 acc[FR][FR];
#pragma unroll
  for (int i = 0; i < FR; i++)
#pragma unroll
    for (int j = 0; j < FR; j++)
#pragma unroll
      for (int r = 0; r < 4; r++) acc[i][j][r] = 0.f;

  int bk = 0; long eOff = 0;
  for (int k0 = 0; k0 < K; k0 += 64) {
#pragma unroll
    for (int i = 0; i < IA; i++) gload16(aG[i] + k0, aL[i]);
#pragma unroll
    for (int i = 0; i < IB; i++) gload16(bG[i] + eOff + bk, bL[i]);
    __syncthreads();

#pragma unroll
    for (int s = 0; s < 2; s++) {
      bf16x8 af[FR], bfv[FR];
#pragma unroll
      for (int i = 0; i < FR; i++)
        af[i] = *(const bf16x8*)(AsB + (aOff[i] ^ (s << 6)));
#pragma unroll
      for (int j = 0; j < FR; j++) {
        if constexpr (sizeof(TB) == 2) {
          bfv[j] = *(const bf16x8*)(BsB + (bOff[j] ^ (s << 6)));
        } else {
          int a0 = bOff[j] ^ (s << 7);
          f32x4 lo = *(const f32x4*)(BsB + a0);
          f32x4 hi = *(const f32x4*)(BsB + (a0 ^ 16));
          bf16x8 v;
          v[0]=(bf16)lo[0]; v[1]=(bf16)lo[1]; v[2]=(bf16)lo[2]; v[3]=(bf16)lo[3];
          v[4]=(bf16)hi[0]; v[5]=(bf16)hi[1]; v[6]=(bf16)hi[2]; v[7]=(bf16)hi[3];
          bfv[j] = v;
        }
      }
#pragma unroll
      for (int i = 0; i < FR; i++)
#pragma unroll
        for (int j = 0; j < FR; j++)
          acc[i][j] = __builtin_amdgcn_mfma_f32_16x16x32_bf16(af[i], bfv[j], acc[i][j], 0, 0, 0);
    }
    __syncthreads();

    bk += 64;
    if (kPerE > 0 && bk >= kPerE) { bk = 0; eOff += bExpStride; }
  }

  bf16*  Cb = (bf16*)Cv + (long)z * zC;
  float* Cf = (float*)Cv + (long)z * zC;
  const float* auxp = aux + (long)z * auxZ;
  const int mB = tileM + wr * (TILE / 2) + quad * 4;
  const int nB = tileN + wc * (TILE / 2) + r16;
#pragma unroll
  for (int i = 0; i < FR; i++) {
#pragma unroll
    for (int r = 0; r < 4; r++) {
      int gm = mB + i * 16 + r;
      if (gm >= M) continue;
      float rowAux = 0.f;
      if constexpr (EPI == EPI_SILU) rowAux = auxp[(long)gm * auxRS];
#pragma unroll
      for (int j = 0; j < FR; j++) {
        int gn = nB + j * 16;
        if (gn >= N) continue;
        float v = acc[i][j][r];
        long off = (long)gm * ldc + gn;
        if constexpr (EPI == EPI_BF16)      Cb[off] = (bf16)v;
        else if constexpr (EPI == EPI_F32)  Cf[off] = v;
        else if constexpr (EPI == EPI_ADD)  Cf[off] = auxp[(long)gm * auxRS + gn] + v;
        else if constexpr (EPI == EPI_SILU) { float sv = v / (1.f + __expf(-v)); Cb[off] = (bf16)(sv * rowAux); }
        else                                atomicAdd(&Cf[off], v);
      }
    }
  }
}

// ---------------------------------------------------------------------------
// 256x256-tile 8-phase pipelined GEMM (bf16 only), C[M,N] (+)= A[M,K] @ B[N,K]^T
//  512 threads = 8 waves (2M x 4N); per-wave 128x64 output (8x4 f32x4 acc).
//  LDS = ring of 8 half-slots (16 KiB each = 128 rows x 64 cols bf16, XOR
//  swizzled): slots {0,1}=B even-tile, {2,3}=A even-tile, {4,5}=B odd,
//  {6,7}=A odd. One half-tile staged per phase via global_load_lds(16B),
//  raw s_barrier (no vmcnt drain), counted s_waitcnt vmcnt(4) only at K-tile
//  boundaries (vmcnt(0) once before the final tile). s_setprio(1) around the
//  16-MFMA cluster of each phase (T3+T4+T5 per the 8-phase template).
//  Stage stream (half s issued at phase s-6, verified WAR/availability):
//   phase0:A0(t+1)->6 p1:A1(t+1)->7 p2:B0(t+2)->0 p3:B1(t+2)->1 [vmcnt4]
//   phase4:A0(t+2)->2 p5:A1(t+2)->3 p6:B0(t+3)->4 p7:B1(t+3)->5 [vmcnt4]
//  Requires: M%256==0, N%256==0, K%128==0 (all uses satisfy exactly).
// ---------------------------------------------------------------------------
template <int EPI>
__global__ void __launch_bounds__(512, 2) gemm256_bt(
    const bf16* __restrict__ A, const bf16* __restrict__ B,
    void* __restrict__ Cv, const float* __restrict__ aux,
    int K, int lda, int ldb, int ldc, long aZ, long bZ)
{
  const int tileN = blockIdx.x * 256;
  const int tileM = blockIdx.y * 256;
  const int z = blockIdx.z;
  A += (long)z * aZ;
  B += (long)z * bZ;

  __shared__ __align__(16) bf16 ring[8 * 8192];   // 8 x 16KiB = 128 KiB
  char* ringB = (char*)ring;

  const int tid  = threadIdx.x;
  const int lane = tid & 63;
  const int wave = tid >> 6;          // 0..7
  const int wr   = wave >> 2;         // 0..1  M-half of the tile
  const int wc   = wave & 3;          // 0..3  N-quarter
  const int quad = lane >> 4, r16 = lane & 15;

  // staging sources: thread covers chunks n = i*512+tid of a 128x64 half-tile
  const bf16* aSrc[2][2];
  const bf16* bSrc[2][2];
#pragma unroll
  for (int i = 0; i < 2; i++) {
    int n = i * 512 + tid;
    int row = n >> 3, cp = n & 7;
    int cc = (cp ^ (row & 7)) << 3;       // swizzled k-chunk (elements)
#pragma unroll
    for (int h = 0; h < 2; h++) {
      aSrc[h][i] = A + (long)(tileM + h * 128 + row) * lda + cc;
      bSrc[h][i] = B + (long)(tileN + h * 128 + row) * ldb + cc;
    }
  }
  const int dstOff = tid * 16;

  auto stageA = [&](int h, int kofs, int slot) {
    gload16(aSrc[h][0] + kofs, ringB + slot * 16384 + dstOff);
    gload16(aSrc[h][1] + kofs, ringB + slot * 16384 + 8192 + dstOff);
  };
  auto stageB = [&](int h, int kofs, int slot) {
    gload16(bSrc[h][0] + kofs, ringB + slot * 16384 + dstOff);
    gload16(bSrc[h][1] + kofs, ringB + slot * 16384 + 8192 + dstOff);
  };

  // ds_read fragment offsets (within a 16 KiB half-slot)
  int aOffB[8], bOffB[4];
#pragma unroll
  for (int i = 0; i < 8; i++) {
    int row = i * 16 + r16;
    aOffB[i] = row * 128 + ((quad ^ (row & 7)) << 4);
  }
#pragma unroll
  for (int j = 0; j < 4; j++) {
    int row = (wc & 1) * 64 + j * 16 + r16;
    bOffB[j] = row * 128 + ((quad ^ (row & 7)) << 4);
  }
  const char* aE = ringB + (2 + wr) * 16384;          // A slots, even tile
  const char* aO = ringB + (6 + wr) * 16384;          // A slots, odd tile
  const char* bE = ringB + ((wc >> 1)) * 16384;       // B slots, even tile
  const char* bO = ringB + (4 + (wc >> 1)) * 16384;   // B slots, odd tile

  f32x4 acc[8][4];
#pragma unroll
  for (int i = 0; i < 8; i++)
#pragma unroll
    for (int j = 0; j < 4; j++)
#pragma unroll
      for (int r = 0; r < 4; r++) acc[i][j][r] = 0.f;

  // prologue: stage tile0 fully + tile1's B halves (6 half-tiles, 12 loads)
  stageB(0, 0, 0); stageB(1, 0, 1); stageA(0, 0, 2); stageA(1, 0, 3);
  stageB(0, 64, 4); stageB(1, 64, 5);
  asm volatile("s_waitcnt vmcnt(4)" ::: "memory");    // tile0 landed
  CFENCE(); __builtin_amdgcn_s_barrier(); CFENCE();

  const int NIT = K >> 7;                              // 2 K-tiles per iter
  for (int it = 0; it < NIT; ++it) {
    const bool last = (it == NIT - 1);
    const int k1 = (2 * it + 1) << 6;
    const int k2 = (2 * it + 2) << 6;
    const int k3 = (2 * it + 3) << 6;
    bf16x8 bfE[4][2], bfO[4][2];

    // ---- even tile 2it: A slots 2+wr, B slots wc>>1 ----
#pragma unroll
    for (int q = 0; q < 4; ++q) {
      bf16x8 af[2][2];
#pragma unroll
      for (int ii = 0; ii < 2; ++ii)
#pragma unroll
        for (int ks = 0; ks < 2; ++ks)
          af[ii][ks] = *(const bf16x8*)(aE + (aOffB[2 * q + ii] ^ (ks << 6)));
      if (q == 0) {
#pragma unroll
        for (int j = 0; j < 4; ++j)
#pragma unroll
          for (int ks = 0; ks < 2; ++ks)
            bfE[j][ks] = *(const bf16x8*)(bE + (bOffB[j] ^ (ks << 6)));
      }
      if (q == 0)      stageA(0, k1, 6);
      else if (q == 1) stageA(1, k1, 7);
      else if (q == 2) { if (!last) stageB(0, k2, 0); }
      else             { if (!last) stageB(1, k2, 1); }
      CFENCE(); __builtin_amdgcn_s_barrier(); CFENCE();
      __builtin_amdgcn_s_setprio(1);
#pragma unroll
      for (int ii = 0; ii < 2; ++ii)
#pragma unroll
        for (int ks = 0; ks < 2; ++ks)
#pragma unroll
          for (int j = 0; j < 4; ++j)
            acc[2 * q + ii][j] = __builtin_amdgcn_mfma_f32_16x16x32_bf16(
                af[ii][ks], bfE[j][ks], acc[2 * q + ii][j], 0, 0, 0);
      __builtin_amdgcn_s_setprio(0);
      if (q == 3) {
        if (last) asm volatile("s_waitcnt vmcnt(0)" ::: "memory");
        else      asm volatile("s_waitcnt vmcnt(4)" ::: "memory");
      }
      CFENCE(); __builtin_amdgcn_s_barrier(); CFENCE();
    }

    // ---- odd tile 2it+1: A slots 6+wr, B slots 4+(wc>>1) ----
#pragma unroll
    for (int q = 0; q < 4; ++q) {
      bf16x8 af[2][2];
#pragma unroll
      for (int ii = 0; ii < 2; ++ii)
#pragma unroll
        for (int ks = 0; ks < 2; ++ks)
          af[ii][ks] = *(const bf16x8*)(aO + (aOffB[2 * q + ii] ^ (ks << 6)));
      if (q == 0) {
#pragma unroll
        for (int j = 0; j < 4; ++j)
#pragma unroll
          for (int ks = 0; ks < 2; ++ks)
            bfO[j][ks] = *(const bf16x8*)(bO + (bOffB[j] ^ (ks << 6)));
      }
      if (!last) {
        if (q == 0)      stageA(0, k2, 2);
        else if (q == 1) stageA(1, k2, 3);
        else if (q == 2) stageB(0, k3, 4);
        else             stageB(1, k3, 5);
      }
      CFENCE(); __builtin_amdgcn_s_barrier(); CFENCE();
      __builtin_amdgcn_s_setprio(1);
#pragma unroll
      for (int ii = 0; ii < 2; ++ii)
#pragma unroll
        for (int ks = 0; ks < 2; ++ks)
#pragma unroll
          for (int j = 0; j < 4; ++j)
            acc[2 * q + ii][j] = __builtin_amdgcn_mfma_f32_16x16x32_bf16(
                af[ii][ks], bfO[j][ks], acc[2 * q + ii][j], 0, 0, 0);
      __builtin_amdgcn_s_setprio(0);
      if (q == 3 && !last) asm volatile("s_waitcnt vmcnt(4)" ::: "memory");
      CFENCE(); __builtin_amdgcn_s_barrier(); CFENCE();
    }
  }

  // epilogue (shapes divide exactly; no bounds checks)
  bf16*  Cb = (bf16*)Cv;
  float* Cf = (float*)Cv;
  const int mB = tileM + wr * 128 + quad * 4;
  const int nB = tileN + wc * 64 + r16;
#pragma unroll
  for (int i = 0; i < 8; ++i) {
#pragma unroll
    for (int r = 0; r < 4; ++r) {
      const int gm = mB + i * 16 + r;
#pragma unroll
      for (int j = 0; j < 4; ++j) {
        const int gn = nB + j * 16;
        float v = acc[i][j][r];
        long off = (long)gm * ldc + gn;
        if constexpr (EPI == EPI_SILU) {
          float sv = v / (1.f + __expf(-v));
          Cb[off] = (bf16)(sv * aux[(long)gm * 8 + (gn / INTER_)]);
        } else if constexpr (EPI == EPI_ATOM) {
          atomicAdd(&Cf[off], v);
        } else {
          Cb[off] = (bf16)v;
        }
      }
    }
  }
}

// ---------------------------------------------------------------------------
// Flash attention (causal): Q,K [NH][S][128], V^T [NH][64][S] -> ctx [S][NH*64]
// grid (NH, S/64); 4 waves, wave w owns q-rows qt*64+w*16..+15.
// ---------------------------------------------------------------------------
__global__ void __launch_bounds__(256) flash_k(
    const bf16* __restrict__ q, const bf16* __restrict__ k,
    const bf16* __restrict__ vt, bf16* __restrict__ ctx, float scale)
{
  const int h  = blockIdx.x;
  const int qt = (int)gridDim.y - 1 - (int)blockIdx.y;   // long blocks first
  const int tid = threadIdx.x, lane = tid & 63, wave = tid >> 6;
  const int quad = lane >> 4, r16 = lane & 15;

  __shared__ __align__(16) bf16 Ks[64 * 128];   // [key][d]  16-chunk swizzle
  __shared__ __align__(16) bf16 Vs[64 * 64];    // [d][key]   8-chunk swizzle
  __shared__ __align__(16) bf16 Ps[4][16 * 64]; // per-wave P, 8-chunk swizzle
  char* KsB = (char*)Ks;
  char* VsB = (char*)Vs;
  char* PsB = (char*)&Ps[wave][0];

  bf16x8 qf[4];
  {
    const bf16* qp = q + ((long)h * S_ + qt * 64 + wave * 16 + r16) * 128 + quad * 8;
#pragma unroll
    for (int ks = 0; ks < 4; ks++) qf[ks] = *(const bf16x8*)(qp + ks * 32);
  }

  const bf16* kG[4]; char* kL[4];
#pragma unroll
  for (int i = 0; i < 4; i++) {
    int n = (wave * 4 + i) * 64 + lane;
    int row = n >> 4, c = n & 15;
    kG[i] = k + ((long)h * S_ + row) * 128 + ((c ^ (row & 15)) << 3);
    kL[i] = KsB + (long)(wave * 4 + i) * 1024;
  }
  const bf16* vG[2]; char* vL[2];
#pragma unroll
  for (int i = 0; i < 2; i++) {
    int n = (wave * 2 + i) * 64 + lane;
    int row = n >> 3, c = n & 7;
    vG[i] = vt + ((long)h * 64 + row) * S_ + ((c ^ (row & 7)) << 3);
    vL[i] = VsB + (long)(wave * 2 + i) * 1024;
  }

  float mr[4], lr[4];
#pragma unroll
  for (int r = 0; r < 4; r++) { mr[r] = -1e30f; lr[r] = 0.f; }
  f32x4 o[4];
#pragma unroll
  for (int j = 0; j < 4; j++)
#pragma unroll
    for (int r = 0; r < 4; r++) o[j][r] = 0.f;

  for (int kt = 0; kt <= qt; kt++) {
#pragma unroll
    for (int i = 0; i < 4; i++) gload16(kG[i] + (long)kt * 64 * 128, kL[i]);
#pragma unroll
    for (int i = 0; i < 2; i++) gload16(vG[i] + kt * 64, vL[i]);
    __syncthreads();

    f32x4 s[4];
#pragma unroll
    for (int j = 0; j < 4; j++)
#pragma unroll
      for (int r = 0; r < 4; r++) s[j][r] = 0.f;
#pragma unroll
    for (int ks = 0; ks < 4; ks++) {
#pragma unroll
      for (int j = 0; j < 4; j++) {
        int row = j * 16 + r16;
        int c = ks * 4 + quad;
        bf16x8 bfr = *(const bf16x8*)(KsB + row * 256 + ((c ^ (row & 15)) << 4));
        s[j] = __builtin_amdgcn_mfma_f32_16x16x32_bf16(qf[ks], bfr, s[j], 0, 0, 0);
      }
    }

    if (kt == qt) {
#pragma unroll
      for (int j = 0; j < 4; j++)
#pragma unroll
        for (int r = 0; r < 4; r++)
          if (j * 16 + r16 > wave * 16 + quad * 4 + r) s[j][r] = -1e30f;
    }

    float pj[4][4];
#pragma unroll
    for (int r = 0; r < 4; r++) {
      float mx = fmaxf(fmaxf(s[0][r], s[1][r]), fmaxf(s[2][r], s[3][r]));
#pragma unroll
      for (int off = 1; off < 16; off <<= 1) mx = fmaxf(mx, __shfl_xor(mx, off, 64));
      mx *= scale;
      float nm = fmaxf(mr[r], mx);
      float alpha = __expf(mr[r] - nm);
      mr[r] = nm;
      float rs = 0.f;
#pragma unroll
      for (int j = 0; j < 4; j++) { float e = __expf(s[j][r] * scale - nm); pj[j][r] = e; rs += e; }
#pragma unroll
      for (int off = 1; off < 16; off <<= 1) rs += __shfl_xor(rs, off, 64);
      lr[r] = lr[r] * alpha + rs;
#pragma unroll
      for (int j = 0; j < 4; j++) o[j][r] *= alpha;
    }

#pragma unroll
    for (int j = 0; j < 4; j++) {
      int chunk = j * 2 + (r16 >> 3);
#pragma unroll
      for (int r = 0; r < 4; r++) {
        int row = quad * 4 + r;
        *(bf16*)(PsB + row * 128 + ((chunk ^ (row & 7)) << 4) + ((r16 & 7) << 1)) = (bf16)pj[j][r];
      }
    }

#pragma unroll
    for (int ks = 0; ks < 2; ks++) {
      int c = ks * 4 + quad;
      bf16x8 af = *(const bf16x8*)(PsB + r16 * 128 + ((c ^ (r16 & 7)) << 4));
#pragma unroll
      for (int j = 0; j < 4; j++) {
        int row = j * 16 + r16;
        bf16x8 bfr = *(const bf16x8*)(VsB + row * 128 + ((c ^ (row & 7)) << 4));
        o[j] = __builtin_amdgcn_mfma_f32_16x16x32_bf16(af, bfr, o[j], 0, 0, 0);
      }
    }
    __syncthreads();
  }

  bf16* cp = ctx + ((long)(qt * 64 + wave * 16 + quad * 4)) * (NH_ * 64) + h * 64 + r16;
#pragma unroll
  for (int r = 0; r < 4; r++) {
    float rl = 1.f / lr[r];
#pragma unroll
    for (int j = 0; j < 4; j++)
      cp[(long)r * NH_ * 64 + j * 16] = (bf16)(o[j][r] * rl);
  }
}

// ---------------------------------------------------------------------------
template <int NIT>
__global__ void __launch_bounds__(256) rmsnorm_k(
    const float* __restrict__ x, const float* __restrict__ w,
    bf16* __restrict__ out, int inStride)
{
  const int row = blockIdx.x, tid = threadIdx.x;
  const float* xr = x + (long)row * inStride;
  float vals[NIT];
  float ss = 0.f;
#pragma unroll
  for (int i = 0; i < NIT; i++) { float v = xr[i * 256 + tid]; vals[i] = v; ss += v * v; }
#pragma unroll
  for (int o = 32; o; o >>= 1) ss += __shfl_xor(ss, o, 64);
  __shared__ float red[4];
  if ((tid & 63) == 0) red[tid >> 6] = ss;
  __syncthreads();
  ss = red[0] + red[1] + red[2] + red[3];
  const float rinv = rsqrtf(ss / (float)(NIT * 256) + EPS_);
  bf16* orow = out + (long)row * (NIT * 256);
#pragma unroll
  for (int i = 0; i < NIT; i++) { int c = i * 256 + tid; orow[c] = (bf16)(w[c] * vals[i] * rinv); }
}

// ---------------------------------------------------------------------------
__global__ void prep_qkv_k(const bf16* __restrict__ q, const bf16* __restrict__ kv,
                           const float* __restrict__ ckv, const int* __restrict__ pos,
                           bf16* __restrict__ query, bf16* __restrict__ key,
                           bf16* __restrict__ vvT)
{
  const int s = blockIdx.x, h = blockIdx.y, d = threadIdx.x;
  const long qkOff = ((long)h * S_ + s) * QH_ + d;
  if (d < 64) {
    query[qkOff] = q[(long)s * H_ + h * QH_ + d];
    key[qkOff]   = kv[(long)s * H_ + h * QH_ + d];
    vvT[((long)h * 64 + d) * S_ + s] = kv[(long)s * H_ + h * QH_ + 64 + d];
  } else {
    const int i = d - 64;
    const float p = (float)pos[s];
    const float invf = powf(10000.f, -(float)(2 * (i & 31)) / 64.f);
    const float ang = p * invf;
    const float cc = cosf(ang), sn = sinf(ang);
    const float xq  = (float)q[(long)s * H_ + h * QH_ + 64 + i];
    const float xqr = (i < 32) ? -(float)q[(long)s * H_ + h * QH_ + 64 + i + 32]
                               :  (float)q[(long)s * H_ + h * QH_ + 64 + i - 32];
    query[qkOff] = (bf16)(xq * cc + xqr * sn);
    const float xk  = ckv[(long)s * 320 + 256 + i];
    const float xkr = (i < 32) ? -ckv[(long)s * 320 + 256 + i + 32]
                               :  ckv[(long)s * 320 + 256 + i - 32];
    key[qkOff] = (bf16)(xk * cc + xkr * sn);
  }
}

// ---------------------------------------------------------------------------
__global__ void __launch_bounds__(256) gate_k(const bf16* __restrict__ mlp,
                                              const float* __restrict__ gw,
                                              float* __restrict__ probs)
{
  const int s = blockIdx.x, tid = threadIdx.x;
  float acc[8];
#pragma unroll
  for (int e = 0; e < 8; e++) acc[e] = 0.f;
  for (int c = tid; c < H_; c += 256) {
    float x = (float)mlp[(long)s * H_ + c];
#pragma unroll
    for (int e = 0; e < 8; e++) acc[e] += x * gw[e * H_ + c];
  }
  __shared__ float red[4][8];
#pragma unroll
  for (int e = 0; e < 8; e++) {
    float v = acc[e];
#pragma unroll
    for (int o = 32; o; o >>= 1) v += __shfl_xor(v, o, 64);
    if ((tid & 63) == 0) red[tid >> 6][e] = v;
  }
  __syncthreads();
  if (tid == 0) {
    float l[8]; float mx = -1e30f;
#pragma unroll
    for (int e = 0; e < 8; e++) { l[e] = red[0][e] + red[1][e] + red[2][e] + red[3][e]; mx = fmaxf(mx, l[e]); }
    float sum = 0.f;
#pragma unroll
    for (int e = 0; e < 8; e++) { l[e] = __expf(l[e] - mx); sum += l[e]; }
    float r = 1.f / sum;
#pragma unroll
    for (int e = 0; e < 8; e++) probs[(long)s * 8 + e] = l[e] * r;
  }
}

// ---------------------------------------------------------------------------
__global__ void __launch_bounds__(256) wconv_k(const float* __restrict__ in,
                                               bf16* __restrict__ out, int n8)
{
  int i = blockIdx.x * 256 + threadIdx.x;
  if (i < n8) {
    f32x4 a = ((const f32x4*)in)[2 * i];
    f32x4 b = ((const f32x4*)in)[2 * i + 1];
    bf16x8 v;
    v[0] = (bf16)a[0]; v[1] = (bf16)a[1]; v[2] = (bf16)a[2]; v[3] = (bf16)a[3];
    v[4] = (bf16)b[0]; v[5] = (bf16)b[1]; v[6] = (bf16)b[2]; v[7] = (bf16)b[3];
    ((bf16x8*)out)[i] = v;
  }
}

// ---------------------------------------------------------------------------
extern "C" void kernel_launch(void* const* d_in, const int* in_sizes, int n_in,
                              void* d_out, int out_size, void* d_ws, size_t ws_size,
                              hipStream_t stream)
{
  const int*   positions = (const int*)  d_in[0];
  const float* hidden    = (const float*)d_in[1];
  const float* ln1       = (const float*)d_in[2];
  const float* wq        = (const float*)d_in[3];
  const float* wkva      = (const float*)d_in[4];
  const float* lnkv      = (const float*)d_in[5];
  const float* wkvb      = (const float*)d_in[6];
  const float* wo        = (const float*)d_in[7];
  const float* ln2       = (const float*)d_in[8];
  const float* wg        = (const float*)d_in[9];
  const float* wfc1      = (const float*)d_in[10];
  const float* wfc2      = (const float*)d_in[11];
  float* out = (float*)d_out;

  char* wsb = (char*)d_ws;
  size_t off = 0;
  auto alloc = [&](size_t bytes) -> void* {
    void* p = wsb + off;
    off += (bytes + 255) & ~(size_t)255;
    return p;
  };
  bf16*  sa_in = (bf16*) alloc((size_t)S_ * H_ * 2);
  bf16*  qb    = (bf16*) alloc((size_t)S_ * H_ * 2);
  float* ckv   = (float*)alloc((size_t)S_ * 320 * 4);
  bf16*  ckvn  = (bf16*) alloc((size_t)S_ * KV_RANK_ * 2);
  bf16*  kvb   = (bf16*) alloc((size_t)S_ * H_ * 2);
  bf16*  query = (bf16*) alloc((size_t)NH_ * S_ * QH_ * 2);
  bf16*  key   = (bf16*) alloc((size_t)NH_ * S_ * QH_ * 2);
  bf16*  vvT   = (bf16*) alloc((size_t)NH_ * 64 * S_ * 2);
  bf16*  ctx   = (bf16*) alloc((size_t)S_ * NH_ * 64 * 2);
  bf16*  mlp   = (bf16*) alloc((size_t)S_ * H_ * 2);
  float* probs = (float*)alloc((size_t)S_ * 8 * 4);
  bf16*  hbuf  = (bf16*) alloc((size_t)S_ * EXP_ * INTER_ * 2);

  const size_t MBy = (size_t)1 << 20;
  const size_t rem = (ws_size > off) ? ws_size - off : 0;
  const size_t szMoeW = (size_t)EXP_ * INTER_ * H_ * 2;      // 46.1 MB each
  const bool cw = (rem >= 93 * MBy);

  bf16* fc1b = nullptr; bf16* fc2b = nullptr;
  if (cw) { fc1b = (bf16*)alloc(szMoeW); fc2b = (bf16*)alloc(szMoeW); }
  // attention weights (bf16) alias hbuf (dead until fc1; o_proj finishes first)
  bf16* wqb   = (bf16*)hbuf;
  bf16* wkvab = wqb   + (size_t)H_ * H_;
  bf16* wkvbb = wkvab + (size_t)320 * H_;
  bf16* wob   = wkvbb + (size_t)H_ * KV_RANK_;

  const float scale = 0.08838834764831845f;   // 128^-0.5

  rmsnorm_k<8><<<S_, 256, 0, stream>>>(hidden, ln1, sa_in, H_);

  if (cw) {
    wconv_k<<<(H_*H_/8 + 255)/256, 256, 0, stream>>>(wq, wqb, H_*H_/8);
    wconv_k<<<(320*H_/8 + 255)/256, 256, 0, stream>>>(wkva, wkvab, 320*H_/8);
    wconv_k<<<(H_*KV_RANK_/8 + 255)/256, 256, 0, stream>>>(wkvb, wkvbb, H_*KV_RANK_/8);
    wconv_k<<<(H_*NH_*64/8 + 255)/256, 256, 0, stream>>>(wo, wob, H_*NH_*64/8);
    wconv_k<<<(EXP_*INTER_*H_/8 + 255)/256, 256, 0, stream>>>(wfc1, fc1b, EXP_*INTER_*H_/8);
    wconv_k<<<(EXP_*INTER_*H_/8 + 255)/256, 256, 0, stream>>>(wfc2, fc2b, EXP_*INTER_*H_/8);
  }

  // q_proj [2048x2048, K=2048]
  if (cw) gemm_bt<EPI_BF16, bf16, 64><<<dim3(32,32,1), 256, 0, stream>>>(
      sa_in, wqb, qb, hidden, S_, H_, H_, H_, H_, H_, 0,0,0,0,0, 0,0,0);
  else    gemm_bt<EPI_BF16, float, 64><<<dim3(32,32,1), 256, 0, stream>>>(
      sa_in, wq,  qb, hidden, S_, H_, H_, H_, H_, H_, 0,0,0,0,0, 0,0,0);

  // kv_a [2048x320, K=2048] -> fp32
  if (cw) gemm_bt<EPI_F32, bf16, 64><<<dim3(5,32,1), 256, 0, stream>>>(
      sa_in, wkvab, ckv, hidden, S_, 320, H_, H_, H_, 320, 0,0,0,0,0, 0,0,0);
  else    gemm_bt<EPI_F32, float, 64><<<dim3(5,32,1), 256, 0, stream>>>(
      sa_in, wkva,  ckv, hidden, S_, 320, H_, H_, H_, 320, 0,0,0,0,0, 0,0,0);

  rmsnorm_k<1><<<S_, 256, 0, stream>>>(ckv, lnkv, ckvn, 320);

  // kv_b [2048x2048, K=256]
  if (cw) gemm_bt<EPI_BF16, bf16, 64><<<dim3(32,32,1), 256, 0, stream>>>(
      ckvn, wkvbb, kvb, hidden, S_, H_, KV_RANK_, KV_RANK_, KV_RANK_, H_, 0,0,0,0,0, 0,0,0);
  else    gemm_bt<EPI_BF16, float, 64><<<dim3(32,32,1), 256, 0, stream>>>(
      ckvn, wkvb,  kvb, hidden, S_, H_, KV_RANK_, KV_RANK_, KV_RANK_, H_, 0,0,0,0,0, 0,0,0);

  prep_qkv_k<<<dim3(S_, NH_), 128, 0, stream>>>(qb, kvb, ckv, positions, query, key, vvT);

  // fused causal attention -> ctx
  flash_k<<<dim3(NH_, S_/64), 256, 0, stream>>>(query, key, vvT, ctx, scale);

  // o_proj: out = hidden + ctx @ wo^T   (writes d_out directly)
  if (cw) gemm_bt<EPI_ADD, bf16, 64><<<dim3(32,32,1), 256, 0, stream>>>(
      ctx, wob, out, hidden, S_, H_, NH_*64, NH_*64, NH_*64, H_, 0,0,0,0, H_, 0,0,0);
  else    gemm_bt<EPI_ADD, float, 64><<<dim3(32,32,1), 256, 0, stream>>>(
      ctx, wo,  out, hidden, S_, H_, NH_*64, NH_*64, NH_*64, H_, 0,0,0,0, H_, 0,0,0);

  rmsnorm_k<8><<<S_, 256, 0, stream>>>(out, ln2, mlp, H_);
  gate_k<<<S_, 256, 0, stream>>>(mlp, wg, probs);

  if (cw) {
    // fc1 as one flat-N dense GEMM: B = fc1_w viewed as [E*INTER=11264][H],
    // C = hbuf [S][11264]; expert for probs-scale = gn/INTER in epilogue.
    // M=2048 (8 tiles) x N=11264 (44 tiles) -> 352 blocks, 8-phase 256^2.
    gemm256_bt<EPI_SILU><<<dim3(44, 8, 1), 512, 0, stream>>>(
        mlp, fc1b, hbuf, probs, H_, H_, H_, EXP_*INTER_, 0, 0);
    // fc2: z=8 (one expert each), K=1408, atomicAdd fp32 into out.
    // A = hbuf cols [z*1408, +1408), B = fc2_w[z] [H][INTER]. 512 blocks.
    gemm256_bt<EPI_ATOM><<<dim3(8, 8, 8), 512, 0, stream>>>(
        hbuf, fc2b, out, nullptr, INTER_, EXP_*INTER_, INTER_, H_,
        (long)INTER_, (long)H_*INTER_);
  } else {
    gemm_bt<EPI_SILU, float, 128><<<dim3(11,16,8), 256, 0, stream>>>(
        mlp, wfc1, hbuf, probs, S_, INTER_, H_, H_, H_, EXP_*INTER_,
        0, (long)INTER_*H_, INTER_, 1, 8, 0, 0, 0);
    gemm_bt<EPI_ATOM, float, 128><<<dim3(16,16,8), 256, 0, stream>>>(
        hbuf, wfc2, out, hidden, S_, H_, INTER_, EXP_*INTER_, 0, H_,
        (long)INTER_, 0, 0, 0, 0, INTER_, (long)H_*INTER_, 1);
  }
}

// Round 2
// 730.267 us; speedup vs baseline: 1.0514x; 1.0514x over previous
//
#include <hip/hip_runtime.h>
#include <cstdint>
#include <cstddef>

typedef __bf16 bf16;
typedef __bf16 bf16x8 __attribute__((ext_vector_type(8)));
typedef float  f32x4  __attribute__((ext_vector_type(4)));

constexpr int S_      = 2048;
constexpr int H_      = 2048;
constexpr int NH_     = 16;
constexpr int KV_RANK_= 256;
constexpr int EXP_    = 8;
constexpr int INTER_  = 1408;
constexpr int QH_     = 128;
constexpr float EPS_  = 1e-6f;

__device__ inline void gload16(const void* g, void* l) {
  __builtin_amdgcn_global_load_lds(
      (const __attribute__((address_space(1))) void*)g,
      (__attribute__((address_space(3))) void*)l, 16, 0, 0);
}

enum { EPI_BF16 = 0, EPI_F32 = 1, EPI_ADD = 2, EPI_SILU = 3, EPI_ATOM = 4 };

// ---------------------------------------------------------------------------
// MFMA GEMM: C[M,N] (+)= A[M,K] @ B[N,K]^T   (BK=64, TILE in {64,128})
//  4 waves as 2x2, each wave (TILE/2)^2 via FRxFRx2 mfma_f32_16x16x32_bf16.
//  XOR-swizzled LDS (conflict-free), staging via global_load_lds width=16.
//  kPerE>0: flat-K MoE, B base hops every kPerE cols by bExpStride.
// ---------------------------------------------------------------------------
template <int EPI, typename TB, int TILE>
__global__ void __launch_bounds__(256, 3) gemm_bt(
    const bf16* __restrict__ A, const TB* __restrict__ B,
    void* __restrict__ Cv, const float* __restrict__ aux,
    int M, int N, int K, int lda, int ldb, int ldc,
    long zA, long zB, long zC, long auxZ, int auxRS,
    int kPerE, long bExpStride, int expBasePerZ)
{
  constexpr int FR = TILE / 32;
  const int tileN = blockIdx.x * TILE;
  const int tileM = blockIdx.y * TILE;
  const int z = blockIdx.z;
  A += (long)z * zA;

  __shared__ __align__(16) bf16 As[TILE * 64];
  __shared__ __align__(16) TB   Bs[TILE * 64];
  char* AsB = (char*)As;
  char* BsB = (char*)Bs;

  const int tid  = threadIdx.x;
  const int lane = tid & 63;
  const int wave = tid >> 6;
  const int wr = wave >> 1, wc = wave & 1;
  const int quad = lane >> 4, r16 = lane & 15;

  const int ldbe = (kPerE > 0) ? kPerE : ldb;
  const TB* BzBase = (kPerE > 0) ? (B + (long)z * expBasePerZ * bExpStride)
                                 : (B + (long)z * zB);

  constexpr int IA = TILE / 32;
  const bf16* aG[IA]; char* aL[IA];
#pragma unroll
  for (int i = 0; i < IA; i++) {
    int n = (wave * IA + i) * 64 + lane;
    int row = n >> 3, cp = n & 7;
    int cc = (cp ^ (row & 7)) << 3;
    int rowg = tileM + row; if (rowg > M - 1) rowg = M - 1;
    aG[i] = A + (long)rowg * lda + cc;
    aL[i] = AsB + (long)(wave * IA + i) * 1024;
  }
  constexpr int IB = (sizeof(TB) == 4) ? (TILE / 16) : (TILE / 32);
  const TB* bG[IB]; char* bL[IB];
#pragma unroll
  for (int i = 0; i < IB; i++) {
    int n = (wave * IB + i) * 64 + lane;
    int row, cc;
    if constexpr (sizeof(TB) == 4) { row = n >> 4; cc = ((n & 15) ^ (row & 15)) << 2; }
    else                           { row = n >> 3; cc = ((n & 7)  ^ (row & 7))  << 3; }
    int rowg = tileN + row; if (rowg > N - 1) rowg = N - 1;
    bG[i] = BzBase + (long)rowg * ldbe + cc;
    bL[i] = BsB + (long)(wave * IB + i) * 1024;
  }

  int aOff[FR], bOff[FR];
#pragma unroll
  for (int i = 0; i < FR; i++) {
    int row = wr * (TILE / 2) + i * 16 + r16;
    aOff[i] = row * 128 + ((quad ^ (row & 7)) << 4);
  }
#pragma unroll
  for (int j = 0; j < FR; j++) {
    int row = wc * (TILE / 2) + j * 16 + r16;
    if constexpr (sizeof(TB) == 4) bOff[j] = row * 256 + (((2 * quad) ^ (row & 15)) << 4);
    else                           bOff[j] = row * 128 + ((quad ^ (row & 7)) << 4);
  }

  f32x4 acc[FR][FR];
#pragma unroll
  for (int i = 0; i < FR; i++)
#pragma unroll
    for (int j = 0; j < FR; j++)
#pragma unroll
      for (int r = 0; r < 4; r++) acc[i][j][r] = 0.f;

  int bk = 0; long eOff = 0;
  for (int k0 = 0; k0 < K; k0 += 64) {
#pragma unroll
    for (int i = 0; i < IA; i++) gload16(aG[i] + k0, aL[i]);
#pragma unroll
    for (int i = 0; i < IB; i++) gload16(bG[i] + eOff + bk, bL[i]);
    __syncthreads();

#pragma unroll
    for (int s = 0; s < 2; s++) {
      bf16x8 af[FR], bfv[FR];
#pragma unroll
      for (int i = 0; i < FR; i++)
        af[i] = *(const bf16x8*)(AsB + (aOff[i] ^ (s << 6)));
#pragma unroll
      for (int j = 0; j < FR; j++) {
        if constexpr (sizeof(TB) == 2) {
          bfv[j] = *(const bf16x8*)(BsB + (bOff[j] ^ (s << 6)));
        } else {
          int a0 = bOff[j] ^ (s << 7);
          f32x4 lo = *(const f32x4*)(BsB + a0);
          f32x4 hi = *(const f32x4*)(BsB + (a0 ^ 16));
          bf16x8 v;
          v[0]=(bf16)lo[0]; v[1]=(bf16)lo[1]; v[2]=(bf16)lo[2]; v[3]=(bf16)lo[3];
          v[4]=(bf16)hi[0]; v[5]=(bf16)hi[1]; v[6]=(bf16)hi[2]; v[7]=(bf16)hi[3];
          bfv[j] = v;
        }
      }
#pragma unroll
      for (int i = 0; i < FR; i++)
#pragma unroll
        for (int j = 0; j < FR; j++)
          acc[i][j] = __builtin_amdgcn_mfma_f32_16x16x32_bf16(af[i], bfv[j], acc[i][j], 0, 0, 0);
    }
    __syncthreads();

    bk += 64;
    if (kPerE > 0 && bk >= kPerE) { bk = 0; eOff += bExpStride; }
  }

  bf16*  Cb = (bf16*)Cv + (long)z * zC;
  float* Cf = (float*)Cv + (long)z * zC;
  const float* auxp = aux + (long)z * auxZ;
  const int mB = tileM + wr * (TILE / 2) + quad * 4;
  const int nB = tileN + wc * (TILE / 2) + r16;
#pragma unroll
  for (int i = 0; i < FR; i++) {
#pragma unroll
    for (int r = 0; r < 4; r++) {
      int gm = mB + i * 16 + r;
      if (gm >= M) continue;
      float rowAux = 0.f;
      if constexpr (EPI == EPI_SILU) rowAux = auxp[(long)gm * auxRS];
#pragma unroll
      for (int j = 0; j < FR; j++) {
        int gn = nB + j * 16;
        if (gn >= N) continue;
        float v = acc[i][j][r];
        long off = (long)gm * ldc + gn;
        if constexpr (EPI == EPI_BF16)      Cb[off] = (bf16)v;
        else if constexpr (EPI == EPI_F32)  Cf[off] = v;
        else if constexpr (EPI == EPI_ADD)  Cf[off] = auxp[(long)gm * auxRS + gn] + v;
        else if constexpr (EPI == EPI_SILU) { float sv = v / (1.f + __expf(-v)); Cb[off] = (bf16)(sv * rowAux); }
        else                                atomicAdd(&Cf[off], v);
      }
    }
  }
}

// ---------------------------------------------------------------------------
// Flash attention (causal): Q,K [NH][S][128], V^T [NH][64][S] -> ctx [S][NH*64]
// grid (NH, S/64); 4 waves, wave w owns q-rows qt*64+w*16..+15.
// ---------------------------------------------------------------------------
__global__ void __launch_bounds__(256) flash_k(
    const bf16* __restrict__ q, const bf16* __restrict__ k,
    const bf16* __restrict__ vt, bf16* __restrict__ ctx, float scale)
{
  const int h  = blockIdx.x;
  const int qt = (int)gridDim.y - 1 - (int)blockIdx.y;   // long blocks first
  const int tid = threadIdx.x, lane = tid & 63, wave = tid >> 6;
  const int quad = lane >> 4, r16 = lane & 15;

  __shared__ __align__(16) bf16 Ks[64 * 128];   // [key][d]  16-chunk swizzle
  __shared__ __align__(16) bf16 Vs[64 * 64];    // [d][key]   8-chunk swizzle
  __shared__ __align__(16) bf16 Ps[4][16 * 64]; // per-wave P, 8-chunk swizzle
  char* KsB = (char*)Ks;
  char* VsB = (char*)Vs;
  char* PsB = (char*)&Ps[wave][0];

  bf16x8 qf[4];
  {
    const bf16* qp = q + ((long)h * S_ + qt * 64 + wave * 16 + r16) * 128 + quad * 8;
#pragma unroll
    for (int ks = 0; ks < 4; ks++) qf[ks] = *(const bf16x8*)(qp + ks * 32);
  }

  const bf16* kG[4]; char* kL[4];
#pragma unroll
  for (int i = 0; i < 4; i++) {
    int n = (wave * 4 + i) * 64 + lane;
    int row = n >> 4, c = n & 15;
    kG[i] = k + ((long)h * S_ + row) * 128 + ((c ^ (row & 15)) << 3);
    kL[i] = KsB + (long)(wave * 4 + i) * 1024;
  }
  const bf16* vG[2]; char* vL[2];
#pragma unroll
  for (int i = 0; i < 2; i++) {
    int n = (wave * 2 + i) * 64 + lane;
    int row = n >> 3, c = n & 7;
    vG[i] = vt + ((long)h * 64 + row) * S_ + ((c ^ (row & 7)) << 3);
    vL[i] = VsB + (long)(wave * 2 + i) * 1024;
  }

  float mr[4], lr[4];
#pragma unroll
  for (int r = 0; r < 4; r++) { mr[r] = -1e30f; lr[r] = 0.f; }
  f32x4 o[4];
#pragma unroll
  for (int j = 0; j < 4; j++)
#pragma unroll
    for (int r = 0; r < 4; r++) o[j][r] = 0.f;

  for (int kt = 0; kt <= qt; kt++) {
#pragma unroll
    for (int i = 0; i < 4; i++) gload16(kG[i] + (long)kt * 64 * 128, kL[i]);
#pragma unroll
    for (int i = 0; i < 2; i++) gload16(vG[i] + kt * 64, vL[i]);
    __syncthreads();

    f32x4 s[4];
#pragma unroll
    for (int j = 0; j < 4; j++)
#pragma unroll
      for (int r = 0; r < 4; r++) s[j][r] = 0.f;
#pragma unroll
    for (int ks = 0; ks < 4; ks++) {
#pragma unroll
      for (int j = 0; j < 4; j++) {
        int row = j * 16 + r16;
        int c = ks * 4 + quad;
        bf16x8 bfr = *(const bf16x8*)(KsB + row * 256 + ((c ^ (row & 15)) << 4));
        s[j] = __builtin_amdgcn_mfma_f32_16x16x32_bf16(qf[ks], bfr, s[j], 0, 0, 0);
      }
    }

    if (kt == qt) {
#pragma unroll
      for (int j = 0; j < 4; j++)
#pragma unroll
        for (int r = 0; r < 4; r++)
          if (j * 16 + r16 > wave * 16 + quad * 4 + r) s[j][r] = -1e30f;
    }

    float pj[4][4];
#pragma unroll
    for (int r = 0; r < 4; r++) {
      float mx = fmaxf(fmaxf(s[0][r], s[1][r]), fmaxf(s[2][r], s[3][r]));
#pragma unroll
      for (int off = 1; off < 16; off <<= 1) mx = fmaxf(mx, __shfl_xor(mx, off, 64));
      mx *= scale;
      float nm = fmaxf(mr[r], mx);
      float alpha = __expf(mr[r] - nm);
      mr[r] = nm;
      float rs = 0.f;
#pragma unroll
      for (int j = 0; j < 4; j++) { float e = __expf(s[j][r] * scale - nm); pj[j][r] = e; rs += e; }
#pragma unroll
      for (int off = 1; off < 16; off <<= 1) rs += __shfl_xor(rs, off, 64);
      lr[r] = lr[r] * alpha + rs;
#pragma unroll
      for (int j = 0; j < 4; j++) o[j][r] *= alpha;
    }

#pragma unroll
    for (int j = 0; j < 4; j++) {
      int chunk = j * 2 + (r16 >> 3);
#pragma unroll
      for (int r = 0; r < 4; r++) {
        int row = quad * 4 + r;
        *(bf16*)(PsB + row * 128 + ((chunk ^ (row & 7)) << 4) + ((r16 & 7) << 1)) = (bf16)pj[j][r];
      }
    }

#pragma unroll
    for (int ks = 0; ks < 2; ks++) {
      int c = ks * 4 + quad;
      bf16x8 af = *(const bf16x8*)(PsB + r16 * 128 + ((c ^ (r16 & 7)) << 4));
#pragma unroll
      for (int j = 0; j < 4; j++) {
        int row = j * 16 + r16;
        bf16x8 bfr = *(const bf16x8*)(VsB + row * 128 + ((c ^ (row & 7)) << 4));
        o[j] = __builtin_amdgcn_mfma_f32_16x16x32_bf16(af, bfr, o[j], 0, 0, 0);
      }
    }
    __syncthreads();
  }

  bf16* cp = ctx + ((long)(qt * 64 + wave * 16 + quad * 4)) * (NH_ * 64) + h * 64 + r16;
#pragma unroll
  for (int r = 0; r < 4; r++) {
    float rl = 1.f / lr[r];
#pragma unroll
    for (int j = 0; j < 4; j++)
      cp[(long)r * NH_ * 64 + j * 16] = (bf16)(o[j][r] * rl);
  }
}

// ---------------------------------------------------------------------------
template <int NIT>
__global__ void __launch_bounds__(256) rmsnorm_k(
    const float* __restrict__ x, const float* __restrict__ w,
    bf16* __restrict__ out, int inStride)
{
  const int row = blockIdx.x, tid = threadIdx.x;
  const float* xr = x + (long)row * inStride;
  float vals[NIT];
  float ss = 0.f;
#pragma unroll
  for (int i = 0; i < NIT; i++) { float v = xr[i * 256 + tid]; vals[i] = v; ss += v * v; }
#pragma unroll
  for (int o = 32; o; o >>= 1) ss += __shfl_xor(ss, o, 64);
  __shared__ float red[4];
  if ((tid & 63) == 0) red[tid >> 6] = ss;
  __syncthreads();
  ss = red[0] + red[1] + red[2] + red[3];
  const float rinv = rsqrtf(ss / (float)(NIT * 256) + EPS_);
  bf16* orow = out + (long)row * (NIT * 256);
#pragma unroll
  for (int i = 0; i < NIT; i++) { int c = i * 256 + tid; orow[c] = (bf16)(w[c] * vals[i] * rinv); }
}

// ---------------------------------------------------------------------------
__global__ void prep_qkv_k(const bf16* __restrict__ q, const bf16* __restrict__ kv,
                           const float* __restrict__ ckv, const int* __restrict__ pos,
                           bf16* __restrict__ query, bf16* __restrict__ key,
                           bf16* __restrict__ vvT)
{
  const int s = blockIdx.x, h = blockIdx.y, d = threadIdx.x;
  const long qkOff = ((long)h * S_ + s) * QH_ + d;
  if (d < 64) {
    query[qkOff] = q[(long)s * H_ + h * QH_ + d];
    key[qkOff]   = kv[(long)s * H_ + h * QH_ + d];
    vvT[((long)h * 64 + d) * S_ + s] = kv[(long)s * H_ + h * QH_ + 64 + d];
  } else {
    const int i = d - 64;
    const float p = (float)pos[s];
    const float invf = powf(10000.f, -(float)(2 * (i & 31)) / 64.f);
    const float ang = p * invf;
    const float cc = cosf(ang), sn = sinf(ang);
    const float xq  = (float)q[(long)s * H_ + h * QH_ + 64 + i];
    const float xqr = (i < 32) ? -(float)q[(long)s * H_ + h * QH_ + 64 + i + 32]
                               :  (float)q[(long)s * H_ + h * QH_ + 64 + i - 32];
    query[qkOff] = (bf16)(xq * cc + xqr * sn);
    const float xk  = ckv[(long)s * 320 + 256 + i];
    const float xkr = (i < 32) ? -ckv[(long)s * 320 + 256 + i + 32]
                               :  ckv[(long)s * 320 + 256 + i - 32];
    key[qkOff] = (bf16)(xk * cc + xkr * sn);
  }
}

// ---------------------------------------------------------------------------
__global__ void __launch_bounds__(256) gate_k(const bf16* __restrict__ mlp,
                                              const float* __restrict__ gw,
                                              float* __restrict__ probs)
{
  const int s = blockIdx.x, tid = threadIdx.x;
  float acc[8];
#pragma unroll
  for (int e = 0; e < 8; e++) acc[e] = 0.f;
  for (int c = tid; c < H_; c += 256) {
    float x = (float)mlp[(long)s * H_ + c];
#pragma unroll
    for (int e = 0; e < 8; e++) acc[e] += x * gw[e * H_ + c];
  }
  __shared__ float red[4][8];
#pragma unroll
  for (int e = 0; e < 8; e++) {
    float v = acc[e];
#pragma unroll
    for (int o = 32; o; o >>= 1) v += __shfl_xor(v, o, 64);
    if ((tid & 63) == 0) red[tid >> 6][e] = v;
  }
  __syncthreads();
  if (tid == 0) {
    float l[8]; float mx = -1e30f;
#pragma unroll
    for (int e = 0; e < 8; e++) { l[e] = red[0][e] + red[1][e] + red[2][e] + red[3][e]; mx = fmaxf(mx, l[e]); }
    float sum = 0.f;
#pragma unroll
    for (int e = 0; e < 8; e++) { l[e] = __expf(l[e] - mx); sum += l[e]; }
    float r = 1.f / sum;
#pragma unroll
    for (int e = 0; e < 8; e++) probs[(long)s * 8 + e] = l[e] * r;
  }
}

// ---------------------------------------------------------------------------
__global__ void __launch_bounds__(256) wconv_k(const float* __restrict__ in,
                                               bf16* __restrict__ out, int n8)
{
  int i = blockIdx.x * 256 + threadIdx.x;
  if (i < n8) {
    f32x4 a = ((const f32x4*)in)[2 * i];
    f32x4 b = ((const f32x4*)in)[2 * i + 1];
    bf16x8 v;
    v[0] = (bf16)a[0]; v[1] = (bf16)a[1]; v[2] = (bf16)a[2]; v[3] = (bf16)a[3];
    v[4] = (bf16)b[0]; v[5] = (bf16)b[1]; v[6] = (bf16)b[2]; v[7] = (bf16)b[3];
    ((bf16x8*)out)[i] = v;
  }
}

// ---------------------------------------------------------------------------
extern "C" void kernel_launch(void* const* d_in, const int* in_sizes, int n_in,
                              void* d_out, int out_size, void* d_ws, size_t ws_size,
                              hipStream_t stream)
{
  const int*   positions = (const int*)  d_in[0];
  const float* hidden    = (const float*)d_in[1];
  const float* ln1       = (const float*)d_in[2];
  const float* wq        = (const float*)d_in[3];
  const float* wkva      = (const float*)d_in[4];
  const float* lnkv      = (const float*)d_in[5];
  const float* wkvb      = (const float*)d_in[6];
  const float* wo        = (const float*)d_in[7];
  const float* ln2       = (const float*)d_in[8];
  const float* wg        = (const float*)d_in[9];
  const float* wfc1      = (const float*)d_in[10];
  const float* wfc2      = (const float*)d_in[11];
  float* out = (float*)d_out;

  char* wsb = (char*)d_ws;
  size_t off = 0;
  auto alloc = [&](size_t bytes) -> void* {
    void* p = wsb + off;
    off += (bytes + 255) & ~(size_t)255;
    return p;
  };
  bf16*  sa_in = (bf16*) alloc((size_t)S_ * H_ * 2);
  bf16*  qb    = (bf16*) alloc((size_t)S_ * H_ * 2);
  float* ckv   = (float*)alloc((size_t)S_ * 320 * 4);
  bf16*  ckvn  = (bf16*) alloc((size_t)S_ * KV_RANK_ * 2);
  bf16*  kvb   = (bf16*) alloc((size_t)S_ * H_ * 2);
  bf16*  query = (bf16*) alloc((size_t)NH_ * S_ * QH_ * 2);
  bf16*  key   = (bf16*) alloc((size_t)NH_ * S_ * QH_ * 2);
  bf16*  vvT   = (bf16*) alloc((size_t)NH_ * 64 * S_ * 2);
  bf16*  ctx   = (bf16*) alloc((size_t)S_ * NH_ * 64 * 2);
  bf16*  mlp   = (bf16*) alloc((size_t)S_ * H_ * 2);
  float* probs = (float*)alloc((size_t)S_ * 8 * 4);
  bf16*  hbuf  = (bf16*) alloc((size_t)S_ * EXP_ * INTER_ * 2);

  const size_t MBy = (size_t)1 << 20;
  const size_t rem = (ws_size > off) ? ws_size - off : 0;
  const size_t szMoeW = (size_t)EXP_ * INTER_ * H_ * 2;      // 46.1 MB each
  const bool cw = (rem >= 93 * MBy);

  bf16* fc1b = nullptr; bf16* fc2b = nullptr;
  if (cw) { fc1b = (bf16*)alloc(szMoeW); fc2b = (bf16*)alloc(szMoeW); }
  // attention weights (bf16) alias hbuf (dead until fc1; o_proj finishes first)
  bf16* wqb   = (bf16*)hbuf;
  bf16* wkvab = wqb   + (size_t)H_ * H_;
  bf16* wkvbb = wkvab + (size_t)320 * H_;
  bf16* wob   = wkvbb + (size_t)H_ * KV_RANK_;

  const float scale = 0.08838834764831845f;   // 128^-0.5

  rmsnorm_k<8><<<S_, 256, 0, stream>>>(hidden, ln1, sa_in, H_);

  if (cw) {
    wconv_k<<<(H_*H_/8 + 255)/256, 256, 0, stream>>>(wq, wqb, H_*H_/8);
    wconv_k<<<(320*H_/8 + 255)/256, 256, 0, stream>>>(wkva, wkvab, 320*H_/8);
    wconv_k<<<(H_*KV_RANK_/8 + 255)/256, 256, 0, stream>>>(wkvb, wkvbb, H_*KV_RANK_/8);
    wconv_k<<<(H_*NH_*64/8 + 255)/256, 256, 0, stream>>>(wo, wob, H_*NH_*64/8);
    wconv_k<<<(EXP_*INTER_*H_/8 + 255)/256, 256, 0, stream>>>(wfc1, fc1b, EXP_*INTER_*H_/8);
    wconv_k<<<(EXP_*INTER_*H_/8 + 255)/256, 256, 0, stream>>>(wfc2, fc2b, EXP_*INTER_*H_/8);
  }

  // q_proj [2048x2048, K=2048]
  if (cw) gemm_bt<EPI_BF16, bf16, 64><<<dim3(32,32,1), 256, 0, stream>>>(
      sa_in, wqb, qb, hidden, S_, H_, H_, H_, H_, H_, 0,0,0,0,0, 0,0,0);
  else    gemm_bt<EPI_BF16, float, 64><<<dim3(32,32,1), 256, 0, stream>>>(
      sa_in, wq,  qb, hidden, S_, H_, H_, H_, H_, H_, 0,0,0,0,0, 0,0,0);

  // kv_a [2048x320, K=2048] -> fp32
  if (cw) gemm_bt<EPI_F32, bf16, 64><<<dim3(5,32,1), 256, 0, stream>>>(
      sa_in, wkvab, ckv, hidden, S_, 320, H_, H_, H_, 320, 0,0,0,0,0, 0,0,0);
  else    gemm_bt<EPI_F32, float, 64><<<dim3(5,32,1), 256, 0, stream>>>(
      sa_in, wkva,  ckv, hidden, S_, 320, H_, H_, H_, 320, 0,0,0,0,0, 0,0,0);

  rmsnorm_k<1><<<S_, 256, 0, stream>>>(ckv, lnkv, ckvn, 320);

  // kv_b [2048x2048, K=256]
  if (cw) gemm_bt<EPI_BF16, bf16, 64><<<dim3(32,32,1), 256, 0, stream>>>(
      ckvn, wkvbb, kvb, hidden, S_, H_, KV_RANK_, KV_RANK_, KV_RANK_, H_, 0,0,0,0,0, 0,0,0);
  else    gemm_bt<EPI_BF16, float, 64><<<dim3(32,32,1), 256, 0, stream>>>(
      ckvn, wkvb,  kvb, hidden, S_, H_, KV_RANK_, KV_RANK_, KV_RANK_, H_, 0,0,0,0,0, 0,0,0);

  prep_qkv_k<<<dim3(S_, NH_), 128, 0, stream>>>(qb, kvb, ckv, positions, query, key, vvT);

  // fused causal attention -> ctx
  flash_k<<<dim3(NH_, S_/64), 256, 0, stream>>>(query, key, vvT, ctx, scale);

  // o_proj: out = hidden + ctx @ wo^T   (writes d_out directly)
  if (cw) gemm_bt<EPI_ADD, bf16, 64><<<dim3(32,32,1), 256, 0, stream>>>(
      ctx, wob, out, hidden, S_, H_, NH_*64, NH_*64, NH_*64, H_, 0,0,0,0, H_, 0,0,0);
  else    gemm_bt<EPI_ADD, float, 64><<<dim3(32,32,1), 256, 0, stream>>>(
      ctx, wo,  out, hidden, S_, H_, NH_*64, NH_*64, NH_*64, H_, 0,0,0,0, H_, 0,0,0);

  rmsnorm_k<8><<<S_, 256, 0, stream>>>(out, ln2, mlp, H_);
  gate_k<<<S_, 256, 0, stream>>>(mlp, wg, probs);

  // fc1: hbuf[s][e*1408+i] = silu(mlp @ fc1_w[e]^T) * probs[s][e]
  if (cw) gemm_bt<EPI_SILU, bf16, 128><<<dim3(11,16,8), 256, 0, stream>>>(
      mlp, fc1b, hbuf, probs, S_, INTER_, H_, H_, H_, EXP_*INTER_,
      0, (long)INTER_*H_, INTER_, 1, 8, 0, 0, 0);
  else    gemm_bt<EPI_SILU, float, 128><<<dim3(11,16,8), 256, 0, stream>>>(
      mlp, wfc1, hbuf, probs, S_, INTER_, H_, H_, H_, EXP_*INTER_,
      0, (long)INTER_*H_, INTER_, 1, 8, 0, 0, 0);

  // fc2: z=4, each z covers 2 experts flat-K (K=2816, kPerE hop), atomicAdd
  // fp32 into out. Halves atomic out traffic vs z=8; doubles K amortization;
  // keeps 1024 blocks (3/CU occupancy regime).
  // A slice per z: columns [z*2816, +2816) of hbuf via flat ptr offset
  // (valid because lda stays 11264).
  if (cw) gemm_bt<EPI_ATOM, bf16, 128><<<dim3(16,16,4), 256, 0, stream>>>(
      hbuf, fc2b, out, hidden, S_, H_, 2*INTER_, EXP_*INTER_, 0, H_,
      (long)(2*INTER_), 0, 0, 0, 0, INTER_, (long)H_*INTER_, 2);
  else    gemm_bt<EPI_ATOM, float, 128><<<dim3(16,16,4), 256, 0, stream>>>(
      hbuf, wfc2, out, hidden, S_, H_, 2*INTER_, EXP_*INTER_, 0, H_,
      (long)(2*INTER_), 0, 0, 0, 0, INTER_, (long)H_*INTER_, 2);
}